// Round 4
// baseline (228.303 us; speedup 1.0000x reference)
//
#include <hip/hip_runtime.h>

// AutoregBlock: B=1024, DIM=384, HID=64, K=8, G=48, MID=128
// Split design:
//   prep : transpose proj_w, convert down_w/up_w to bf16 (into ws)
//   kernA: per-batch Pg path -> scales (1024 blocks x 512 thr, 72 KB LDS, 2 blk/CU)
//          H in LDS bf16; M-build + Pg MFMA in two K=256 rounds (sM 24 KB, sPg aliases sM)
//   kernB: FFN GEMM over flattened 393216 rows (3072 blocks x 128 rows, 65 KB LDS, 2 blk/CU)
//          H recomputed from x,W,b directly into MFMA A-fragments (no H LDS/global)

#define EPSF 1e-6f

typedef __attribute__((ext_vector_type(8))) short bf16x8;
typedef __attribute__((ext_vector_type(4))) float f32x4;
typedef __attribute__((ext_vector_type(4))) unsigned short u16x4;

__device__ __forceinline__ unsigned short f2bf(float f) {
    union { float f; unsigned int u; } v; v.f = f;
    unsigned int r = v.u + 0x7fffu + ((v.u >> 16) & 1u);
    return (unsigned short)(r >> 16);
}
__device__ __forceinline__ float bf2f(unsigned short h) {
    union { unsigned int u; float f; } v; v.u = ((unsigned int)h) << 16;
    return v.f;
}
__device__ __forceinline__ float leaky(float v) { return fmaxf(v, 0.01f * v); }
__device__ __forceinline__ int key8(int r) { return (r ^ (r >> 3)) & 7; }
__device__ __forceinline__ float gelu_f(float u) {
    float t = u * (1.5957691216f + 0.0713548163f * (u * u));
    float e = __expf(t);
    float rc = __builtin_amdgcn_rcpf(e + 1.0f);
    return fmaf(-u, rc, u);
}

// ws floats: [0,18432) projT (48x384); bf16 dwB 8192 @ +18432, uwB 8192 after;
// scales (1024x384 f32) at float offset 26624.
#define SCALES_OFF 26624

__global__ void prep(const float* __restrict__ proj_w,
                     const float* __restrict__ down_w,
                     const float* __restrict__ up_w,
                     float* __restrict__ ws) {
    int idx = blockIdx.x * blockDim.x + threadIdx.x;
    unsigned short* wb = (unsigned short*)(ws + 18432);
    if (idx < 18432) {
        int i = idx / 48, g = idx % 48;
        ws[g * 384 + i] = proj_w[idx];
    } else if (idx < 26624) {
        int k = idx - 18432;
        wb[k] = f2bf(down_w[k]);
    } else if (idx < 34816) {
        int k = idx - 26624;
        wb[8192 + k] = f2bf(up_w[k]);
    }
}

__global__ __launch_bounds__(512, 4) void kernA(
    const float* __restrict__ x,
    const float* __restrict__ W,
    const float* __restrict__ bb,
    const float* __restrict__ patch_weight,
    const float* __restrict__ pw1, const float* __restrict__ pb1,
    const float* __restrict__ pw2, const float* __restrict__ pb2,
    const float* __restrict__ proj_b,
    const float* __restrict__ ws,
    float* __restrict__ scales)
{
    __shared__ __align__(16) unsigned short sH[24576];  // 48 KB  H bf16 [i][c] swizzled
    __shared__ __align__(16) unsigned short sM[12288];  // 24 KB  M half (48x256) -> sPg
    __shared__ __align__(16) float sw[64];
    __shared__ float srw[48];
    float* sPg = (float*)sM;                            // 48x48 f32 (9216 B), after sM dead

    const int t = threadIdx.x, b = blockIdx.x;
    const int wv = t >> 6, lane = t & 63, q = lane >> 4, r = lane & 15;
    const float* projT = ws;

    // P0: softmax of patch weights (wave 0)
    if (t < 64) {
        float p = patch_weight[t];
        float m = p;
        for (int o = 32; o > 0; o >>= 1) m = fmaxf(m, __shfl_xor(m, o));
        float e = __expf(p - m);
        float s = e;
        for (int o = 32; o > 0; o >>= 1) s += __shfl_xor(s, o);
        sw[t] = e * __builtin_amdgcn_rcpf(s);
    }

    // P1: H = gelu(x*W + inv*b) -> sH bf16 swizzled
    for (int j = 0; j < 12; ++j) {
        int idx4 = j * 512 + t;
        int base = idx4 * 4;
        int i = base >> 6, c0 = base & 63;
        float4 w4 = ((const float4*)W)[idx4];
        float4 b4 = ((const float4*)bb)[idx4];
        float xi  = x[b * 384 + i];
        float inv = __builtin_amdgcn_rcpf(fabsf(xi) + EPSF);
        u16x4 hv;
        hv[0] = f2bf(gelu_f(fmaf(xi, w4.x, inv * b4.x)));
        hv[1] = f2bf(gelu_f(fmaf(xi, w4.y, inv * b4.y)));
        hv[2] = f2bf(gelu_f(fmaf(xi, w4.z, inv * b4.z)));
        hv[3] = f2bf(gelu_f(fmaf(xi, w4.w, inv * b4.w)));
        int cb = c0 >> 3, cc = c0 & 7;
        *(u16x4*)&sH[i * 64 + ((cb ^ key8(i)) << 3) + cc] = hv;
    }
    __syncthreads();

    // P2/P3: two K=256 rounds. Round rnd covers l in [4rnd, 4rnd+4).
    f32x4 pacc[2];
    pacc[0] = (f32x4){0.f, 0.f, 0.f, 0.f};
    pacc[1] = (f32x4){0.f, 0.f, 0.f, 0.f};
    for (int rnd = 0; rnd < 2; ++rnd) {
        // P2: M[g, l_loc*64+c] = sum_k w[k, 4rnd+l_loc]*H[8g+k, c]
        if (t < 384) {
            const int g = t >> 3, cb = t & 7;
            float acc[4][8];
            #pragma unroll
            for (int a = 0; a < 4; ++a)
                #pragma unroll
                for (int cc = 0; cc < 8; ++cc) acc[a][cc] = 0.0f;
            #pragma unroll
            for (int k = 0; k < 8; ++k) {
                int i = g * 8 + k;
                bf16x8 hv = *(const bf16x8*)&sH[i * 64 + ((cb ^ key8(i)) << 3)];
                f32x4 w4 = *(const f32x4*)&sw[k * 8 + rnd * 4];
                float hf[8];
                #pragma unroll
                for (int cc = 0; cc < 8; ++cc) hf[cc] = bf2f((unsigned short)hv[cc]);
                #pragma unroll
                for (int a = 0; a < 4; ++a)
                    #pragma unroll
                    for (int cc = 0; cc < 8; ++cc) acc[a][cc] = fmaf(w4[a], hf[cc], acc[a][cc]);
            }
            #pragma unroll
            for (int a = 0; a < 4; ++a) {
                int blk = a * 8 + cb;                         // block in [0,32)
                int blkS = (blk & ~7) | ((blk ^ key8(g)) & 7);
                bf16x8 mv;
                #pragma unroll
                for (int cc = 0; cc < 8; ++cc) mv[cc] = (short)f2bf(acc[a][cc]);
                *(bf16x8*)&sM[g * 256 + (blkS << 3)] = mv;
            }
        }
        __syncthreads();
        // P3: 9 tiles over 8 waves (wave 0 also takes tile 8); 8 K-steps each
        #pragma unroll
        for (int ti = 0; ti < 2; ++ti) {
            if (ti == 1 && wv != 0) break;
            int tt = (ti == 0) ? wv : 8;
            int tg = tt / 3, th = tt % 3;
            for (int ks = 0; ks < 8; ++ks) {
                int kl = ks * 32 + q * 8;
                int g = tg * 16 + r;
                int blk = kl >> 3;
                int blkS = (blk & ~7) | ((blk ^ key8(g)) & 7);
                bf16x8 av = *(const bf16x8*)&sM[g * 256 + (blkS << 3)];
                int kg = rnd * 256 + kl;
                int i = (th * 16 + r) * 8 + (kg >> 6);
                int c = kg & 63;
                bf16x8 bv = *(const bf16x8*)&sH[i * 64 + (((c >> 3) ^ key8(i)) << 3)];
                pacc[ti] = __builtin_amdgcn_mfma_f32_16x16x32_bf16(av, bv, pacc[ti], 0, 0, 0);
            }
        }
        __syncthreads();   // all P3 reads done; sM reusable
    }

    // P3b: pair ops -> sPg (aliases sM; safe after barrier above)
    #pragma unroll
    for (int ti = 0; ti < 2; ++ti) {
        if (ti == 1 && wv != 0) break;
        int tt = (ti == 0) ? wv : 8;
        int tg = tt / 3, th = tt % 3;
        #pragma unroll
        for (int reg = 0; reg < 4; ++reg) {
            int g = tg * 16 + q * 4 + reg;
            int h = th * 16 + r;
            int idx = g * 48 + h;
            float v = pacc[ti][reg];
            v = leaky(fmaf(v, pw1[idx], pb1[idx]));
            v = leaky(fmaf(v, pw2[idx], pb2[idx]));
            sPg[g * 48 + h] = v;
        }
    }
    __syncthreads();

    // P4: row softmax -> row_weights (6 rows per wave)
    for (int rr = 0; rr < 6; ++rr) {
        int row = wv * 6 + rr;
        float v = (lane < 48) ? sPg[row * 48 + lane] : -1e30f;
        float m = v;
        for (int o = 32; o > 0; o >>= 1) m = fmaxf(m, __shfl_xor(m, o));
        float e = (lane < 48) ? __expf(v - m) : 0.0f;
        float s = e;
        for (int o = 32; o > 0; o >>= 1) s += __shfl_xor(s, o);
        float p = e * __builtin_amdgcn_rcpf(s);
        float rwv = (lane < 48) ? __builtin_amdgcn_rcpf(fmaf(p, p, 1.0f)) : 0.0f;
        for (int o = 32; o > 0; o >>= 1) rwv += __shfl_xor(rwv, o);
        if (lane == 0) srw[row] = rwv;
    }
    __syncthreads();

    // P5: scales[i] = srw . projT[:,i] + proj_b[i] -> global
    if (t < 384) {
        float s = proj_b[t];
        #pragma unroll 4
        for (int g = 0; g < 48; ++g) s = fmaf(srw[g], projT[g * 384 + t], s);
        scales[b * 384 + t] = s;
    }
}

__global__ __launch_bounds__(512, 4) void kernB(
    const float* __restrict__ x,
    const float* __restrict__ W,
    const float* __restrict__ bb,
    const float* __restrict__ down_b,
    const float* __restrict__ up_b,
    const float* __restrict__ ws,
    const float* __restrict__ scales,
    float* __restrict__ out)
{
    __shared__ __align__(16) unsigned short sDW[8192];   // 16 KB 128x64 bf16 swizzled
    __shared__ __align__(16) unsigned short sUW[8192];   // 16 KB 64x128 bf16 swizzled
    __shared__ __align__(16) unsigned short sZ1[16384];  // 32 KB 128x128 bf16 swizzled
    __shared__ float sSc[128], sXv[128], sIv[128], sDb[128], sUb[64];

    const int t = threadIdx.x, blk = blockIdx.x;
    const int wv = t >> 6, lane = t & 63, q = lane >> 4, r = lane & 15;
    const int bIdx = blk / 3, roff = (blk % 3) * 128;
    const unsigned short* dwB = (const unsigned short*)(ws + 18432);
    const unsigned short* uwB = dwB + 8192;

    // stage x/inv/scales/biases + weights
    if (t < 128) {
        float xv = x[bIdx * 384 + roff + t];
        sXv[t] = xv;
        sIv[t] = __builtin_amdgcn_rcpf(fabsf(xv) + EPSF);
        sSc[t] = scales[blk * 128 + t];
        sDb[t] = down_b[t];
    } else if (t < 192) {
        sUb[t - 128] = up_b[t - 128];
    }
    for (int cid = t; cid < 2048; cid += 512) {
        if (cid < 1024) {                      // down_w rows (128x64)
            int nrow = cid >> 3, cb = cid & 7;
            bf16x8 v = *(const bf16x8*)&dwB[cid * 8];
            *(bf16x8*)&sDW[nrow * 64 + ((cb ^ key8(nrow)) << 3)] = v;
        } else {                               // up_w rows (64x128)
            int c2 = cid - 1024;
            int rrow = c2 >> 4, cb = c2 & 15;
            bf16x8 v = *(const bf16x8*)&uwB[c2 * 8];
            int cbs = (cb & 8) | ((cb ^ key8(rrow)) & 7);
            *(bf16x8*)&sUW[rrow * 128 + (cbs << 3)] = v;
        }
    }
    __syncthreads();

    // z1: recompute H directly into A-fragments; z1 = leaky(scale*(H@dw^T)+db)
    const int iloc = wv * 16 + r;
    bf16x8 afr[2];
    {
        float xv = sXv[iloc], iv = sIv[iloc];
        const int i = roff + iloc;
        #pragma unroll
        for (int ks = 0; ks < 2; ++ks) {
            const float4* Wp = (const float4*)&W[i * 64 + ks * 32 + q * 8];
            const float4* Bp = (const float4*)&bb[i * 64 + ks * 32 + q * 8];
            float4 wa = Wp[0], wc = Wp[1], ba = Bp[0], bc = Bp[1];
            bf16x8 af;
            af[0] = (short)f2bf(gelu_f(fmaf(xv, wa.x, iv * ba.x)));
            af[1] = (short)f2bf(gelu_f(fmaf(xv, wa.y, iv * ba.y)));
            af[2] = (short)f2bf(gelu_f(fmaf(xv, wa.z, iv * ba.z)));
            af[3] = (short)f2bf(gelu_f(fmaf(xv, wa.w, iv * ba.w)));
            af[4] = (short)f2bf(gelu_f(fmaf(xv, wc.x, iv * bc.x)));
            af[5] = (short)f2bf(gelu_f(fmaf(xv, wc.y, iv * bc.y)));
            af[6] = (short)f2bf(gelu_f(fmaf(xv, wc.z, iv * bc.z)));
            af[7] = (short)f2bf(gelu_f(fmaf(xv, wc.w, iv * bc.w)));
            afr[ks] = af;
        }
    }
    f32x4 acc[8];
    #pragma unroll
    for (int nt = 0; nt < 8; ++nt) acc[nt] = (f32x4){0.f, 0.f, 0.f, 0.f};
    #pragma unroll
    for (int ks = 0; ks < 2; ++ks) {
        int cb = ks * 4 + q;
        #pragma unroll
        for (int nt = 0; nt < 8; ++nt) {
            int nrow = nt * 16 + r;
            bf16x8 bv = *(const bf16x8*)&sDW[nrow * 64 + ((cb ^ key8(nrow)) << 3)];
            acc[nt] = __builtin_amdgcn_mfma_f32_16x16x32_bf16(afr[ks], bv, acc[nt], 0, 0, 0);
        }
    }
    #pragma unroll
    for (int nt = 0; nt < 8; ++nt) {
        #pragma unroll
        for (int reg = 0; reg < 4; ++reg) {
            int rl = wv * 16 + q * 4 + reg;
            int m = nt * 16 + r;
            float v = leaky(fmaf(acc[nt][reg], sSc[rl], sDb[m]));
            int cb2 = m >> 3;
            int cbs2 = (cb2 & 8) | ((cb2 ^ key8(rl)) & 7);
            sZ1[rl * 128 + (cbs2 << 3) + (m & 7)] = f2bf(v);
        }
    }
    __syncthreads();

    // z2 = leaky(z1 @ uw^T + ub) -> out
    f32x4 a2[4];
    #pragma unroll
    for (int nt = 0; nt < 4; ++nt) a2[nt] = (f32x4){0.f, 0.f, 0.f, 0.f};
    #pragma unroll
    for (int ks = 0; ks < 4; ++ks) {
        int rl = wv * 16 + r;
        int cb = ks * 4 + q;
        int cbsA = (cb & 8) | ((cb ^ key8(rl)) & 7);
        bf16x8 av = *(const bf16x8*)&sZ1[rl * 128 + (cbsA << 3)];
        #pragma unroll
        for (int nt = 0; nt < 4; ++nt) {
            int cp = nt * 16 + r;
            int cbsB = (cb & 8) | ((cb ^ key8(cp)) & 7);
            bf16x8 bv = *(const bf16x8*)&sUW[cp * 128 + (cbsB << 3)];
            a2[nt] = __builtin_amdgcn_mfma_f32_16x16x32_bf16(av, bv, a2[nt], 0, 0, 0);
        }
    }
    #pragma unroll
    for (int nt = 0; nt < 4; ++nt) {
        #pragma unroll
        for (int reg = 0; reg < 4; ++reg) {
            int il = wv * 16 + q * 4 + reg;
            int cp = nt * 16 + r;
            out[(blk * 128 + il) * 64 + cp] = leaky(a2[nt][reg] + sUb[cp]);
        }
    }
}

extern "C" void kernel_launch(void* const* d_in, const int* in_sizes, int n_in,
                              void* d_out, int out_size, void* d_ws, size_t ws_size,
                              hipStream_t stream) {
    const float* x      = (const float*)d_in[0];
    const float* W      = (const float*)d_in[1];
    const float* bb     = (const float*)d_in[2];
    const float* pw     = (const float*)d_in[3];
    const float* pw1    = (const float*)d_in[4];
    const float* pb1    = (const float*)d_in[5];
    const float* pw2    = (const float*)d_in[6];
    const float* pb2    = (const float*)d_in[7];
    const float* proj_w = (const float*)d_in[8];
    const float* proj_b = (const float*)d_in[9];
    const float* down_w = (const float*)d_in[10];
    const float* down_b = (const float*)d_in[11];
    const float* up_w   = (const float*)d_in[12];
    const float* up_b   = (const float*)d_in[13];
    float* out = (float*)d_out;
    float* ws  = (float*)d_ws;
    float* scales = ws + SCALES_OFF;

    prep<<<(34816 + 255) / 256, 256, 0, stream>>>(proj_w, down_w, up_w, ws);
    kernA<<<1024, 512, 0, stream>>>(x, W, bb, pw, pw1, pb1, pw2, pb2,
                                    proj_b, ws, scales);
    kernB<<<3072, 512, 0, stream>>>(x, W, bb, down_b, up_b, ws, scales, out);
}